// Round 6
// baseline (2373.274 us; speedup 1.0000x reference)
//
#include <hip/hip_runtime.h>

// GAWADecoder on MI355X (gfx950). All tensors fp32 in global; bf16 MFMA inside.
// R7 post-mortem: dur and FETCH identical to R6 (repack changed nothing), and
// hbm_gbps is CONSTANT ~2.9 TB/s across R4/R6/R7 -> the loop is pinned at the
// TCC<->LLC fetch-rate ceiling: dur = FETCH/2.9TB/s. FETCH is big because
// demand is big: 256 blocks x 32 steps x 1.18MB = 9.7GB of weight re-reads at
// ~55% L2 hit (per-XCD touched set ~3.7MB vs 4MB L2, 32 drifting streams).
// R8: CUT DEMAND. 128 blocks x 32 rows (2x rows/weight-byte -> 4.8GB demand),
// gword/cproj converted to bf16 (halves the unique streaming side), so the
// per-XCD per-step set drops to ~2.3MB -> L2-resident -> FETCH falls super-
// linearly. Re-phased to fit 128-VGPR cap: phase A = gh0 only (6 fx4 accums),
// phase B = gi1+gh1 together (12 fx4; legal: gh1 reads h1(t-1) which is not
// overwritten until phase-B gates). h-masters live in LDS, not registers.

typedef __bf16 bf16;
typedef __attribute__((ext_vector_type(8))) __bf16 bf16x8;
typedef __attribute__((ext_vector_type(4))) __bf16 bf16x4;
typedef __attribute__((ext_vector_type(4))) float fx4;

#define MFMA16(a, b, c) __builtin_amdgcn_mfma_f32_16x16x32_bf16(a, b, c, 0, 0, 0)

__device__ __forceinline__ float sigm(float x) { return 1.0f / (1.0f + expf(-x)); }

// load 8 consecutive fp32, round to bf16x8 (MFMA operand)
__device__ __forceinline__ bf16x8 cvt8(const float* __restrict__ p) {
    float4 u = ((const float4*)p)[0];
    float4 v = ((const float4*)p)[1];
    bf16x8 r;
    r[0] = (bf16)u.x; r[1] = (bf16)u.y; r[2] = (bf16)u.z; r[3] = (bf16)u.w;
    r[4] = (bf16)v.x; r[5] = (bf16)v.y; r[6] = (bf16)v.z; r[7] = (bf16)v.w;
    return r;
}

// bf16x8 h + fp32[8] -> bf16x8 (logits A-fragment: h1 + attn_out)
__device__ __forceinline__ bf16x8 addcvt8(bf16x8 h, const float* __restrict__ p) {
    float4 u = ((const float4*)p)[0];
    float4 v = ((const float4*)p)[1];
    bf16x8 r;
    r[0] = (bf16)((float)h[0] + u.x); r[1] = (bf16)((float)h[1] + u.y);
    r[2] = (bf16)((float)h[2] + u.z); r[3] = (bf16)((float)h[3] + u.w);
    r[4] = (bf16)((float)h[4] + v.x); r[5] = (bf16)((float)h[5] + v.y);
    r[6] = (bf16)((float)h[6] + v.z); r[7] = (bf16)((float)h[7] + v.w);
    return r;
}

// ---------------------------------------------------------------------------
__global__ void f2b(const float* __restrict__ s, bf16* __restrict__ d, int n) {
    int i = (blockIdx.x * 256 + threadIdx.x) * 4;
    if (i >= n) return;
    float4 v = *(const float4*)(s + i);
    bf16x4 o;
    o[0] = (bf16)v.x; o[1] = (bf16)v.y; o[2] = (bf16)v.z; o[3] = (bf16)v.w;
    *(bf16x4*)(d + i) = o;
}

// ---------------------------------------------------------------------------
// Repack a (768,256) fp32 weight matrix into per-wave linear bf16 slabs:
//   dst elem idx = ((((w*8 + c)*3 + g)*16 + l16)*4 + quad)*8 + e
// (wave w = cols w*16..w*16+16; chunk = 1KB contiguous per wave-load)
// ---------------------------------------------------------------------------
__global__ void wpack(const float* __restrict__ src, bf16* __restrict__ dst) {
    int gid = blockIdx.x * 256 + threadIdx.x;     // 768*32 pieces of 8 elems
    if (gid >= 768 * 32) return;
    int gc = gid >> 5, piece = gid & 31;
    int g = gc >> 8, rem = gc & 255, w = rem >> 4, l16 = rem & 15;
    int c = piece >> 2, quad = piece & 3;
    bf16x8 v = cvt8(src + (size_t)gc * 256 + piece * 8);
    size_t d = (size_t)w * 12288 + (size_t)(c * 3 + g) * 512 + l16 * 32 + quad * 8;
    *(bf16x8*)(dst + d) = v;
}

// ---------------------------------------------------------------------------
// out[M,N] = act(A[M,K] @ W[N,K]^T + bias), fp32 in global; bf16 MFMA inside.
// ---------------------------------------------------------------------------
__global__ __launch_bounds__(256, 4) void gemm_bt(
    const float* __restrict__ A, int lda,
    const float* __restrict__ W, int ldw,
    const float* __restrict__ bias,
    float* __restrict__ out, int ldo, int act_tanh, int K)
{
    const int tid  = threadIdx.x;
    const int wid  = tid >> 6;
    const int lane = tid & 63;
    const int quad = lane >> 4;
    const int l16  = lane & 15;
    const int m0   = blockIdx.x * 32;
    const int n0   = blockIdx.y * 256 + wid * 64;

    fx4 acc[4][2];
#pragma unroll
    for (int j = 0; j < 4; ++j) {
        acc[j][0] = fx4{0.f, 0.f, 0.f, 0.f};
        acc[j][1] = fx4{0.f, 0.f, 0.f, 0.f};
    }

    const float* a0p = A + (size_t)(m0 + l16) * lda + quad * 8;
    const float* a1p = A + (size_t)(m0 + 16 + l16) * lda + quad * 8;

    for (int k0 = 0; k0 < K; k0 += 32) {
        bf16x8 a0 = cvt8(a0p + k0);
        bf16x8 a1 = cvt8(a1p + k0);
#pragma unroll
        for (int j = 0; j < 4; ++j) {
            bf16x8 b = cvt8(W + (size_t)(n0 + j * 16 + l16) * ldw + k0 + quad * 8);
            acc[j][0] = MFMA16(a0, b, acc[j][0]);
            acc[j][1] = MFMA16(a1, b, acc[j][1]);
        }
    }

#pragma unroll
    for (int j = 0; j < 4; ++j) {
        int n = n0 + j * 16 + l16;
        float bv = bias ? bias[n] : 0.0f;
#pragma unroll
        for (int rt = 0; rt < 2; ++rt)
#pragma unroll
            for (int r = 0; r < 4; ++r) {
                int m = m0 + rt * 16 + quad * 4 + r;
                float v = acc[j][rt][r] + bv;
                if (act_tanh) v = tanhf(v);
                out[(size_t)m * ldo + n] = v;
            }
    }
}

// ---------------------------------------------------------------------------
// Persistent recurrent kernel. 128 blocks x 1024 thr (16 waves), 32 rows/block.
// Two barriers/step, block-local LDS ping-pong (no fences). Per wave: 16 cols
// x 32 rows (2 row-tiles). Phase A: gh0 = h0(t-1)@w_hh0^T -> layer-0 gates ->
// h0(t). Phase B: gi1 = h0(t)@w_ih1^T AND gh1 = h1(t-1)@w_hh1^T -> layer-1
// gates -> h1(t) (+NT archive store). Weights stream from per-wave linear
// slabs (1KB bursts); gword/cproj read as bf16. h state lives in LDS only.
// ---------------------------------------------------------------------------
__global__ __launch_bounds__(1024, 4) void decoder_loop(
    const int*   __restrict__ tgt,      // (4096,32)
    const float* __restrict__ h0i,      // (4096,256)
    const bf16*  __restrict__ gwb,      // (4096,768) bf16: eword gi0 part(+b_ih0)
    const bf16*  __restrict__ cpb,      // (256,768)  bf16: char_emb@w_ih0[:,:64]^T
    const bf16*  __restrict__ w_hh0p, const float* __restrict__ b_hh0,
    const bf16*  __restrict__ w_ih1p, const float* __restrict__ b_ih1,
    const bf16*  __restrict__ w_hh1p, const float* __restrict__ b_hh1,
    bf16* __restrict__ h1all)           // (4096,32,256) bf16
{
    __shared__ __align__(16) bf16 hb0[2][32][264];   // 33.8 KB each pair
    __shared__ __align__(16) bf16 hb1[2][32][264];

    const int tid  = threadIdx.x;
    const int wid  = tid >> 6;     // 0..15
    const int lane = tid & 63;
    const int quad = lane >> 4;
    const int l16  = lane & 15;
    const int row0 = blockIdx.x * 32;
    const int col  = wid * 16 + l16;

    // per-wave linear slab bases (lane-fixed offset inside each 1KB chunk)
    const bf16* pW0 = w_hh0p + (size_t)wid * 12288 + l16 * 32 + quad * 8;
    const bf16* pW1 = w_ih1p + (size_t)wid * 12288 + l16 * 32 + quad * 8;
    const bf16* pW2 = w_hh1p + (size_t)wid * 12288 + l16 * 32 + quad * 8;

    float bh0[3], bi1[3], bh1[3];
#pragma unroll
    for (int g = 0; g < 3; ++g) {
        bh0[g] = b_hh0[g * 256 + col];
        bi1[g] = b_ih1[g * 256 + col];
        bh1[g] = b_hh1[g * 256 + col];
    }

    // init h state in LDS (lane covers 8 rows: rt*16 + quad*4 + r)
#pragma unroll
    for (int i = 0; i < 8; ++i) {
        int row_l = (i >> 2) * 16 + quad * 4 + (i & 3);
        float v = h0i[(size_t)(row0 + row_l) * 256 + col];
        bf16 bv = (bf16)v;
        hb0[0][row_l][col] = bv;
        hb1[0][row_l][col] = bv;
    }
    __syncthreads();

    for (int t = 0; t < 32; ++t) {
        const int p = t & 1, q = p ^ 1;

        // -------- cg gather (bf16): gi0 = gword + cproj[id] (issued early) ---
        int ids[8];
#pragma unroll
        for (int i = 0; i < 8; ++i) {
            int row_l = (i >> 2) * 16 + quad * 4 + (i & 3);
            ids[i] = (t == 0) ? 1 : tgt[(row0 + row_l) * 32 + (t - 1)];
        }
        float cgv[3][8];
#pragma unroll
        for (int i = 0; i < 8; ++i) {
            int row_l = (i >> 2) * 16 + quad * 4 + (i & 3);
#pragma unroll
            for (int g = 0; g < 3; ++g)
                cgv[g][i] = (float)cpb[(size_t)ids[i] * 768 + g * 256 + col]
                          + (float)gwb[(size_t)(row0 + row_l) * 768 + g * 256 + col];
        }

        // -------- phase A: gh0 = h0(t-1) @ w_hh0^T (2 row-tiles) --------
        fx4 g0[3][2];
#pragma unroll
        for (int g = 0; g < 3; ++g) {
            g0[g][0] = fx4{0.f, 0.f, 0.f, 0.f};
            g0[g][1] = fx4{0.f, 0.f, 0.f, 0.f};
        }
#pragma unroll
        for (int kk = 0; kk < 8; ++kk) {
            bf16x8 a0 = *(const bf16x8*)&hb0[p][l16][kk * 32 + quad * 8];
            bf16x8 a1 = *(const bf16x8*)&hb0[p][16 + l16][kk * 32 + quad * 8];
#pragma unroll
            for (int g = 0; g < 3; ++g) {
                bf16x8 w = *(const bf16x8*)(pW0 + (kk * 3 + g) * 512);
                g0[g][0] = MFMA16(a0, w, g0[g][0]);
                g0[g][1] = MFMA16(a1, w, g0[g][1]);
            }
        }
        // layer-0 gates -> h0(t) into partner buffer
#pragma unroll
        for (int i = 0; i < 8; ++i) {
            int rt = i >> 2, r = i & 3;
            int row_l = rt * 16 + quad * 4 + r;
            float hold = (float)hb0[p][row_l][col];
            float rr = sigm(cgv[0][i] + g0[0][rt][r] + bh0[0]);
            float zz = sigm(cgv[1][i] + g0[1][rt][r] + bh0[1]);
            float nn = tanhf(cgv[2][i] + rr * (g0[2][rt][r] + bh0[2]));
            hb0[q][row_l][col] = (bf16)((1.0f - zz) * nn + zz * hold);
        }
        __syncthreads();   // B1: h0(t) visible; done reading hb0[p]

        // -------- phase B: gi1 = h0(t)@w_ih1^T ; gh1 = h1(t-1)@w_hh1^T -------
        fx4 gi[3][2], gh[3][2];
#pragma unroll
        for (int g = 0; g < 3; ++g) {
            gi[g][0] = fx4{0.f, 0.f, 0.f, 0.f}; gi[g][1] = fx4{0.f, 0.f, 0.f, 0.f};
            gh[g][0] = fx4{0.f, 0.f, 0.f, 0.f}; gh[g][1] = fx4{0.f, 0.f, 0.f, 0.f};
        }
#pragma unroll
        for (int kk = 0; kk < 8; ++kk) {
            bf16x8 a0 = *(const bf16x8*)&hb0[q][l16][kk * 32 + quad * 8];
            bf16x8 a1 = *(const bf16x8*)&hb0[q][16 + l16][kk * 32 + quad * 8];
            bf16x8 c0 = *(const bf16x8*)&hb1[p][l16][kk * 32 + quad * 8];
            bf16x8 c1 = *(const bf16x8*)&hb1[p][16 + l16][kk * 32 + quad * 8];
#pragma unroll
            for (int g = 0; g < 3; ++g) {
                bf16x8 w1 = *(const bf16x8*)(pW1 + (kk * 3 + g) * 512);
                gi[g][0] = MFMA16(a0, w1, gi[g][0]);
                gi[g][1] = MFMA16(a1, w1, gi[g][1]);
                bf16x8 w2 = *(const bf16x8*)(pW2 + (kk * 3 + g) * 512);
                gh[g][0] = MFMA16(c0, w2, gh[g][0]);
                gh[g][1] = MFMA16(c1, w2, gh[g][1]);
            }
        }
        // layer-1 gates -> h1(t)
#pragma unroll
        for (int i = 0; i < 8; ++i) {
            int rt = i >> 2, r = i & 3;
            int row_l = rt * 16 + quad * 4 + r;
            float hold = (float)hb1[p][row_l][col];
            float rr = sigm(gi[0][rt][r] + bi1[0] + gh[0][rt][r] + bh1[0]);
            float zz = sigm(gi[1][rt][r] + bi1[1] + gh[1][rt][r] + bh1[1]);
            float nn = tanhf(gi[2][rt][r] + bi1[2] + rr * (gh[2][rt][r] + bh1[2]));
            bf16 hv = (bf16)((1.0f - zz) * nn + zz * hold);
            hb1[q][row_l][col] = hv;
            __builtin_nontemporal_store(
                hv, &h1all[((size_t)(row0 + row_l) * 32 + t) * 256 + col]);
        }
        __syncthreads();   // B2: h1(t) visible
    }
}

// ---------------------------------------------------------------------------
// Final logits: out[m,v] = (h1[m,:] + a2[m>>5,:]) @ pw^T + pb[v],  M=131072.
// ---------------------------------------------------------------------------
__global__ __launch_bounds__(256, 4) void logits_final(
    const bf16*  __restrict__ h1,    // (131072,256) bf16
    const float* __restrict__ a2,    // (4096,256) attn_out (fp32)
    const bf16*  __restrict__ pw,    // (256,256) bf16
    const float* __restrict__ pb,    // (256,)
    float* __restrict__ out)         // (131072,256)
{
    const int tid  = threadIdx.x;
    const int wid  = tid >> 6;
    const int lane = tid & 63;
    const int quad = lane >> 4;
    const int l16  = lane & 15;
    const int m0   = blockIdx.x * 32;
    const int n0   = wid * 64;
    const int b    = m0 >> 5;          // all 32 rows share one batch index

    fx4 acc[4][2];
#pragma unroll
    for (int j = 0; j < 4; ++j) {
        acc[j][0] = fx4{0.f, 0.f, 0.f, 0.f};
        acc[j][1] = fx4{0.f, 0.f, 0.f, 0.f};
    }

    for (int k0 = 0; k0 < 256; k0 += 32) {
        bf16x8 h0 = *(const bf16x8*)(h1 + (size_t)(m0 + l16) * 256 + k0 + quad * 8);
        bf16x8 h1v = *(const bf16x8*)(h1 + (size_t)(m0 + 16 + l16) * 256 + k0 + quad * 8);
        const float* ap = a2 + (size_t)b * 256 + k0 + quad * 8;
        bf16x8 a0 = addcvt8(h0, ap);
        bf16x8 a1 = addcvt8(h1v, ap);
#pragma unroll
        for (int j = 0; j < 4; ++j) {
            bf16x8 bb = *(const bf16x8*)(pw + (size_t)(n0 + j * 16 + l16) * 256 + k0 + quad * 8);
            acc[j][0] = MFMA16(a0, bb, acc[j][0]);
            acc[j][1] = MFMA16(a1, bb, acc[j][1]);
        }
    }

#pragma unroll
    for (int j = 0; j < 4; ++j) {
        int n = n0 + j * 16 + l16;
        float bv = pb[n];
#pragma unroll
        for (int rt = 0; rt < 2; ++rt)
#pragma unroll
            for (int r = 0; r < 4; ++r) {
                int m = m0 + rt * 16 + quad * 4 + r;
                out[(size_t)m * 256 + n] = acc[j][rt][r] + bv;
            }
    }
}

// ---------------------------------------------------------------------------
extern "C" void kernel_launch(void* const* d_in, const int* in_sizes, int n_in,
                              void* d_out, int out_size, void* d_ws, size_t ws_size,
                              hipStream_t stream)
{
    const float* eword      = (const float*)d_in[0];
    const int*   tgt        = (const int*)  d_in[1];
    const float* char_emb   = (const float*)d_in[2];
    const float* ew_w       = (const float*)d_in[3];
    const float* ew_b       = (const float*)d_in[4];
    const float* w_ih0      = (const float*)d_in[5];   // (768, 832)
    const float* w_hh0      = (const float*)d_in[6];
    const float* b_ih0      = (const float*)d_in[7];
    const float* b_hh0      = (const float*)d_in[8];
    const float* w_ih1      = (const float*)d_in[9];
    const float* w_hh1      = (const float*)d_in[10];
    const float* b_ih1      = (const float*)d_in[11];
    const float* b_hh1      = (const float*)d_in[12];
    const float* attn_in_w  = (const float*)d_in[13];  // wq|wk|wv (q,k dead)
    const float* attn_in_b  = (const float*)d_in[14];
    const float* attn_out_w = (const float*)d_in[15];
    const float* attn_out_b = (const float*)d_in[16];
    // d_in[17..18] key_w/key_b dead (len-1 softmax)
    const float* val_w      = (const float*)d_in[19];
    const float* val_b      = (const float*)d_in[20];
    const float* proj_w     = (const float*)d_in[21];
    const float* proj_b     = (const float*)d_in[22];

    char* ws = (char*)d_ws;
    float* h0i   = (float*)ws;  ws += (size_t)4096 * 256 * 4;   //  4 MB
    float* gwrd  = (float*)ws;  ws += (size_t)4096 * 768 * 4;   // 12 MB
    float* cproj = (float*)ws;  ws += (size_t)256  * 768 * 4;   // .75 MB
    float* a2    = (float*)ws;  ws += (size_t)4096 * 256 * 4;   //  4 MB
    // 8 MB region: prologue uses it as fp32 buf1/buf2; decoder reuses it as
    // bf16 gwb (6 MB) + cpb (0.375 MB) — stream-ordered, no overlap.
    char*  hreg  = ws;          ws += (size_t)8 * 1024 * 1024;
    float* buf1  = (float*)hreg;                          // 4 MB (t1)
    float* buf2  = (float*)(hreg + (size_t)4*1024*1024);  // 4 MB (ev)
    bf16*  gwb   = (bf16*)hreg;                           // (4096,768) bf16
    bf16*  cpb   = (bf16*)(hreg + (size_t)6*1024*1024);   // (256,768) bf16
    bf16*  wbhh0 = (bf16*)ws;   ws += (size_t)768 * 256 * 2;    // packed slabs
    bf16*  wbih1 = (bf16*)ws;   ws += (size_t)768 * 256 * 2;
    bf16*  wbhh1 = (bf16*)ws;   ws += (size_t)768 * 256 * 2;
    bf16*  wbprj = (bf16*)ws;   ws += (size_t)256 * 256 * 2;
    bf16*  h1all = (bf16*)ws;   ws += (size_t)4096 * 32 * 256 * 2;  // 67 MB

    dim3 blk(256);
    // pack loop weights into per-wave linear slabs (bf16)
    wpack<<<dim3(96), blk, 0, stream>>>(w_hh0, wbhh0);
    wpack<<<dim3(96), blk, 0, stream>>>(w_ih1, wbih1);
    wpack<<<dim3(96), blk, 0, stream>>>(w_hh1, wbhh1);
    f2b<<<dim3(64),  blk, 0, stream>>>(proj_w, wbprj, 256 * 256);

    // h0 = tanh(eword @ ew_w^T + ew_b)
    gemm_bt<<<dim3(128, 1), blk, 0, stream>>>(eword, 768, ew_w, 768, ew_b, h0i, 256, 1, 768);
    // gword = eword @ w_ih0[:,64:]^T + b_ih0
    gemm_bt<<<dim3(128, 3), blk, 0, stream>>>(eword, 768, w_ih0 + 64, 832, b_ih0, gwrd, 768, 0, 768);
    // cproj = char_emb @ w_ih0[:,:64]^T   (PAD row of char_emb is zero)
    gemm_bt<<<dim3(8, 3),   blk, 0, stream>>>(char_emb, 64, w_ih0, 832, nullptr, cproj, 768, 0, 64);
    // attention chain (static): t1 = ew@vw^T+vb; ev = t1@wv^T+bv; a2 = ev@ao^T+ab
    gemm_bt<<<dim3(128, 1), blk, 0, stream>>>(eword, 768, val_w, 768, val_b, buf1, 256, 0, 768);
    gemm_bt<<<dim3(128, 1), blk, 0, stream>>>(buf1, 256, attn_in_w + 512 * 256, 256, attn_in_b + 512, buf2, 256, 0, 256);
    gemm_bt<<<dim3(128, 1), blk, 0, stream>>>(buf2, 256, attn_out_w, 256, attn_out_b, a2, 256, 0, 256);

    // bf16 conversions for the loop's streaming side (after buf1/buf2 retire)
    f2b<<<dim3(3072), blk, 0, stream>>>(gwrd, gwb, 4096 * 768);
    f2b<<<dim3(192),  blk, 0, stream>>>(cproj, cpb, 256 * 768);

    // recurrent decode: 128 blocks x 32 rows (halved weight demand)
    decoder_loop<<<dim3(128), dim3(1024), 0, stream>>>(
        tgt, h0i, gwb, cpb,
        wbhh0, b_hh0, wbih1, b_ih1, wbhh1, b_hh1, h1all);

    // batched logits: out = (h1 + a2) @ pw^T + pb
    logits_final<<<dim3(4096), blk, 0, stream>>>(h1all, a2, wbprj, proj_b, (float*)d_out);
}